// Round 1
// baseline (159.121 us; speedup 1.0000x reference)
//
#include <hip/hip_runtime.h>
#include <stdint.h>

// Problem constants (from reference)
#define BATCH   8192
#define IN_DIM  256
#define OUT_DIM 64
#define NROW    68      // 67 spline bases + 1 silu row per d
#define N_SPLIT 16      // d-splits
#define D_SLICE 16      // d's per block (256/N_SPLIT)
#define D_STAGE 4       // d's staged in LDS at once
#define N_STAGE 4       // stages per block
#define M_BLK   256     // batch rows per block
#define NM      32      // 8192/M_BLK

typedef unsigned int u32;

__device__ __forceinline__ u32 f2bf(float f) {              // f32 -> bf16 (RNE)
    u32 u = __float_as_uint(f);
    u += 0x7FFFu + ((u >> 16) & 1u);
    return u >> 16;
}
__device__ __forceinline__ float bflo(u32 u) { return __uint_as_float(u << 16); }
__device__ __forceinline__ float bfhi(u32 u) { return __uint_as_float(u & 0xFFFF0000u); }

// knot t[i], i in [0,70]: 3 clamped zeros, linspace(0,1,65), 3 clamped ones.
// (i-3)/64 is exact in fp32 -> matches jnp.linspace bit-exactly.
__device__ __forceinline__ float knotf(int i) {
    return fminf(1.f, fmaxf(0.f, (float)(i - 3) * 0.015625f));
}

// Windowed Cox-de Boor (Piegl&Tiller BasisFuns, degree 3).
// Packs record: {c0|c1 bf16, c2|c3 bf16, silu f32, s u32}
__device__ __forceinline__ void make_record(float x, u32 rec[4]) {
    int s = (int)floorf(x * 64.f);
    s = max(0, min(63, s));
    const int m = s + 3;
    float N0 = 1.f, N1, N2, N3;
    const float l1 = x - knotf(m);
    const float r1 = knotf(m + 1) - x;
    {
        float tmp = N0 / (r1 + l1);
        N0 = r1 * tmp;
        N1 = l1 * tmp;
    }
    const float l2 = x - knotf(m - 1);
    const float r2 = knotf(m + 2) - x;
    {
        float tmp = N0 / (r1 + l2);
        N0 = r1 * tmp;
        float saved = l2 * tmp;
        tmp = N1 / (r2 + l1);
        N1 = saved + r2 * tmp;
        N2 = l1 * tmp;
    }
    const float l3 = x - knotf(m - 2);
    const float r3 = knotf(m + 3) - x;
    {
        float tmp = N0 / (r1 + l3);
        N0 = r1 * tmp;
        float saved = l3 * tmp;
        tmp = N1 / (r2 + l2);
        N1 = saved + r2 * tmp;
        saved = l2 * tmp;
        tmp = N2 / (r3 + l1);
        N2 = saved + r3 * tmp;
        N3 = l1 * tmp;
    }
    const float silu = x / (1.f + __expf(-x));
    rec[0] = f2bf(N0) | (f2bf(N1) << 16);
    rec[1] = f2bf(N2) | (f2bf(N3) << 16);
    rec[2] = __float_as_uint(silu);
    rec[3] = (u32)s;
}

// LDS layout (51200 B total):
//   [0, 34816):      w stage, 4 d's: per d 68 rows x 64 bf16, row stride 128 B,
//                    16B-slot XOR swizzle: slot = (o>>3) ^ (row&7)
//   [34816, 51200):  coeff records [4 dl][256 r] x 16 B
#define W_LDS_BYTES   34816
#define D_LDS_BYTES   8704

__global__ __launch_bounds__(512, 4)
void kan_main(const float* __restrict__ X, const float* __restrict__ W,
              float* __restrict__ outbuf, int useAtomic) {
    __shared__ uint4 smem4[3200];
    char* sm = (char*)smem4;

    const int mb  = blockIdx.x;          // 0..31
    const int sp  = blockIdx.y;          // 0..15
    const int tid = threadIdx.x;
    const int r0  = mb * M_BLK;
    const int d0  = sp * D_SLICE;

    const int lane = tid & 63;
    const int wv   = tid >> 6;           // wave 0..7
    const int sub  = lane & 7;           // o-chunk (8 outputs, b128)
    const int g    = lane >> 3;          // row-in-round 0..7
    const int rb   = wv * 32;            // wave's local row base

    float acc[4][8];
#pragma unroll
    for (int t = 0; t < 4; ++t)
#pragma unroll
        for (int k = 0; k < 8; ++k) acc[t][k] = 0.f;

    for (int st = 0; st < N_STAGE; ++st) {
        const int ds = d0 + st * D_STAGE;
        __syncthreads();   // prev stage's readers done before overwrite

        // ---- stage w (4 d's = 17408 f32) -> bf16 LDS, swizzled ----
        {
            const float4* wg = (const float4*)(W + (size_t)ds * (NROW * OUT_DIM));
            for (int i = tid; i < (D_STAGE * NROW * OUT_DIM / 4); i += 512) {
                float4 v = wg[i];
                int e   = i * 4;
                int dl  = e / (NROW * OUT_DIM);
                int rem = e - dl * (NROW * OUT_DIM);
                int row = rem >> 6;
                int o0  = rem & 63;
                u32 lo = f2bf(v.x) | (f2bf(v.y) << 16);
                u32 hi = f2bf(v.z) | (f2bf(v.w) << 16);
                int byte = dl * D_LDS_BYTES + row * 128
                         + ((((o0 >> 3) ^ (row & 7)) << 4)) + (o0 & 7) * 2;
                *(uint2*)(sm + byte) = make_uint2(lo, hi);
            }
        }
        // ---- coeff records: 256 rows x 4 d (each thread: 1 row, 2 d's) ----
        {
            const int r  = tid & 255;
            const int dh = tid >> 8;     // 0..1
            const float2 xv = *(const float2*)(X + (size_t)(r0 + r) * IN_DIM + ds + dh * 2);
            u32 rec[4];
            make_record(xv.x, rec);
            *(uint4*)(sm + W_LDS_BYTES + (((dh * 2 + 0) * 256 + r) << 4)) =
                make_uint4(rec[0], rec[1], rec[2], rec[3]);
            make_record(xv.y, rec);
            *(uint4*)(sm + W_LDS_BYTES + (((dh * 2 + 1) * 256 + r) << 4)) =
                make_uint4(rec[0], rec[1], rec[2], rec[3]);
        }
        __syncthreads();

        // ---- gather-FMA over 4 d's x 32 rows/wave ----
#pragma unroll
        for (int dl = 0; dl < D_STAGE; ++dl) {
            const int dBase = dl * D_LDS_BYTES;
            // hoist silu weight row (row 67) for this d
            uint4 wp = *(const uint4*)(sm + dBase + 67 * 128 + ((sub ^ 3) << 4));
            float w67f[8];
            w67f[0] = bflo(wp.x); w67f[1] = bfhi(wp.x);
            w67f[2] = bflo(wp.y); w67f[3] = bfhi(wp.y);
            w67f[4] = bflo(wp.z); w67f[5] = bfhi(wp.z);
            w67f[6] = bflo(wp.w); w67f[7] = bfhi(wp.w);
#pragma unroll
            for (int t = 0; t < 4; ++t) {
                uint4 rec = *(const uint4*)(sm + W_LDS_BYTES +
                                            ((dl * 256 + rb + t * 8 + g) << 4));
                const float c[4] = { bflo(rec.x), bfhi(rec.x), bflo(rec.y), bfhi(rec.y) };
                const float silu = __uint_as_float(rec.z);
                const int sbase  = (int)rec.w;
#pragma unroll
                for (int j = 0; j < 4; ++j) {
                    const int row = sbase + j;
                    uint4 wr = *(const uint4*)(sm + dBase + row * 128 +
                                               (((sub ^ (row & 7)) << 4)));
                    const float cj = c[j];
                    acc[t][0] = fmaf(cj, bflo(wr.x), acc[t][0]);
                    acc[t][1] = fmaf(cj, bfhi(wr.x), acc[t][1]);
                    acc[t][2] = fmaf(cj, bflo(wr.y), acc[t][2]);
                    acc[t][3] = fmaf(cj, bfhi(wr.y), acc[t][3]);
                    acc[t][4] = fmaf(cj, bflo(wr.z), acc[t][4]);
                    acc[t][5] = fmaf(cj, bfhi(wr.z), acc[t][5]);
                    acc[t][6] = fmaf(cj, bflo(wr.w), acc[t][6]);
                    acc[t][7] = fmaf(cj, bfhi(wr.w), acc[t][7]);
                }
#pragma unroll
                for (int k = 0; k < 8; ++k)
                    acc[t][k] = fmaf(silu, w67f[k], acc[t][k]);
            }
        }
    }

    // ---- emit partials ----
    if (!useAtomic) {
        float* wsp = outbuf + (size_t)sp * (BATCH * OUT_DIM);
#pragma unroll
        for (int t = 0; t < 4; ++t) {
            const int R = r0 + rb + t * 8 + g;
            *(float4*)(wsp + (size_t)R * 64 + sub * 8) =
                make_float4(acc[t][0], acc[t][1], acc[t][2], acc[t][3]);
            *(float4*)(wsp + (size_t)R * 64 + sub * 8 + 4) =
                make_float4(acc[t][4], acc[t][5], acc[t][6], acc[t][7]);
        }
    } else {
#pragma unroll
        for (int t = 0; t < 4; ++t) {
            const int R = r0 + rb + t * 8 + g;
#pragma unroll
            for (int k = 0; k < 8; ++k)
                atomicAdd(outbuf + (size_t)R * 64 + sub * 8 + k, acc[t][k]);
        }
    }
}

__global__ __launch_bounds__(256)
void kan_reduce(const float* __restrict__ ws, float* __restrict__ out) {
    const int i = blockIdx.x * 256 + threadIdx.x;   // float4 index, 131072 total
    const float4* w4 = (const float4*)ws;
    float4 a = w4[i];
#pragma unroll
    for (int s = 1; s < N_SPLIT; ++s) {
        float4 b = w4[(size_t)s * (BATCH * OUT_DIM / 4) + i];
        a.x += b.x; a.y += b.y; a.z += b.z; a.w += b.w;
    }
    ((float4*)out)[i] = a;
}

extern "C" void kernel_launch(void* const* d_in, const int* in_sizes, int n_in,
                              void* d_out, int out_size, void* d_ws, size_t ws_size,
                              hipStream_t stream) {
    const float* X = (const float*)d_in[0];
    const float* W = (const float*)d_in[1];
    float* out = (float*)d_out;
    const size_t need = (size_t)N_SPLIT * BATCH * OUT_DIM * sizeof(float);
    dim3 grid(NM, N_SPLIT);
    if (ws_size >= need) {
        kan_main<<<grid, 512, 0, stream>>>(X, W, (float*)d_ws, 0);
        kan_reduce<<<(BATCH * OUT_DIM / 4) / 256, 256, 0, stream>>>((const float*)d_ws, out);
    } else {
        hipMemsetAsync(d_out, 0, (size_t)out_size * sizeof(float), stream);
        kan_main<<<grid, 512, 0, stream>>>(X, W, out, 1);
    }
}

// Round 3
// 84.046 us; speedup vs baseline: 1.8933x; 1.8933x over previous
//
#include <hip/hip_runtime.h>
#include <stdint.h>

// Problem constants (from reference)
#define BATCH   8192
#define IN_DIM  256
#define OUT_DIM 64
#define NROW    68      // 67 spline bases + 1 silu row per d
#define N_SPLIT 16      // d-splits
#define D_SLICE 16      // d's per block (256/N_SPLIT)
#define D_STAGE 4       // d's staged in LDS at once
#define N_STAGE 4       // stages per block
#define M_BLK   256     // batch rows per block
#define NM      32      // 8192/M_BLK

typedef unsigned int u32;
typedef float f32x4 __attribute__((ext_vector_type(4)));   // native vec for nontemporal builtins

__device__ __forceinline__ u32 f2bf(float f) {              // f32 -> bf16 (RNE)
    u32 u = __float_as_uint(f);
    u += 0x7FFFu + ((u >> 16) & 1u);
    return u >> 16;
}
__device__ __forceinline__ float bflo(u32 u) { return __uint_as_float(u << 16); }
__device__ __forceinline__ float bfhi(u32 u) { return __uint_as_float(u & 0xFFFF0000u); }

// knot t[i], i in [0,70]: 3 clamped zeros, linspace(0,1,65), 3 clamped ones.
// (i-3)/64 is exact in fp32 -> matches jnp.linspace bit-exactly.
__device__ __forceinline__ float knotf(int i) {
    return fminf(1.f, fmaxf(0.f, (float)(i - 3) * 0.015625f));
}

// Windowed Cox-de Boor (Piegl&Tiller BasisFuns, degree 3).
// Packs record: {c0|c1 bf16, c2|c3 bf16, silu f32, s u32}
__device__ __forceinline__ void make_record(float x, u32 rec[4]) {
    int s = (int)floorf(x * 64.f);
    s = max(0, min(63, s));
    const int m = s + 3;
    float N0 = 1.f, N1, N2, N3;
    const float l1 = x - knotf(m);
    const float r1 = knotf(m + 1) - x;
    {
        float tmp = N0 / (r1 + l1);
        N0 = r1 * tmp;
        N1 = l1 * tmp;
    }
    const float l2 = x - knotf(m - 1);
    const float r2 = knotf(m + 2) - x;
    {
        float tmp = N0 / (r1 + l2);
        N0 = r1 * tmp;
        float saved = l2 * tmp;
        tmp = N1 / (r2 + l1);
        N1 = saved + r2 * tmp;
        N2 = l1 * tmp;
    }
    const float l3 = x - knotf(m - 2);
    const float r3 = knotf(m + 3) - x;
    {
        float tmp = N0 / (r1 + l3);
        N0 = r1 * tmp;
        float saved = l3 * tmp;
        tmp = N1 / (r2 + l2);
        N1 = saved + r2 * tmp;
        saved = l2 * tmp;
        tmp = N2 / (r3 + l1);
        N2 = saved + r3 * tmp;
        N3 = l1 * tmp;
    }
    const float silu = x / (1.f + __expf(-x));
    rec[0] = f2bf(N0) | (f2bf(N1) << 16);
    rec[1] = f2bf(N2) | (f2bf(N3) << 16);
    rec[2] = __float_as_uint(silu);
    rec[3] = (u32)s;
}

// LDS layout (51200 B total):
//   [0, 34816):      w stage, 4 d's: per d 68 rows x 64 bf16, row stride 128 B,
//                    16B-slot XOR swizzle: slot = (o>>3) ^ (row&7)
//   [34816, 51200):  coeff records [4 dl][256 r] x 16 B
#define W_LDS_BYTES   34816
#define D_LDS_BYTES   8704

// launch_bounds(512, 2): min 2 waves/EU -> VGPR cap 256. R1 lesson: (512,4)
// capped VGPRs at 64 and the hot loop spilled ~400 MB of scratch writebacks
// per dispatch (WRITE_SIZE 435 MB vs 33.5 MB of real stores).
__global__ __launch_bounds__(512, 2)
void kan_main(const float* __restrict__ X, const float* __restrict__ W,
              float* __restrict__ outbuf, int useAtomic) {
    __shared__ uint4 smem4[3200];
    char* sm = (char*)smem4;

    const int mb  = blockIdx.x;          // 0..31
    const int sp  = blockIdx.y;          // 0..15
    const int tid = threadIdx.x;
    const int r0  = mb * M_BLK;
    const int d0  = sp * D_SLICE;

    const int lane = tid & 63;
    const int wv   = tid >> 6;           // wave 0..7
    const int sub  = lane & 7;           // o-chunk (8 outputs, b128)
    const int g    = lane >> 3;          // row-in-round 0..7
    const int rb   = wv * 32;            // wave's local row base

    float acc[4][8];
#pragma unroll
    for (int t = 0; t < 4; ++t)
#pragma unroll
        for (int k = 0; k < 8; ++k) acc[t][k] = 0.f;

    for (int st = 0; st < N_STAGE; ++st) {
        const int ds = d0 + st * D_STAGE;
        __syncthreads();   // prev stage's readers done before overwrite

        // ---- stage w (4 d's = 17408 f32) -> bf16 LDS, swizzled ----
        {
            const float4* wg = (const float4*)(W + (size_t)ds * (NROW * OUT_DIM));
            for (int i = tid; i < (D_STAGE * NROW * OUT_DIM / 4); i += 512) {
                float4 v = wg[i];
                int e   = i * 4;
                int dl  = e / (NROW * OUT_DIM);
                int rem = e - dl * (NROW * OUT_DIM);
                int row = rem >> 6;
                int o0  = rem & 63;
                u32 lo = f2bf(v.x) | (f2bf(v.y) << 16);
                u32 hi = f2bf(v.z) | (f2bf(v.w) << 16);
                int byte = dl * D_LDS_BYTES + row * 128
                         + ((((o0 >> 3) ^ (row & 7)) << 4)) + (o0 & 7) * 2;
                *(uint2*)(sm + byte) = make_uint2(lo, hi);
            }
        }
        // ---- coeff records: 256 rows x 4 d (each thread: 1 row, 2 d's) ----
        {
            const int r  = tid & 255;
            const int dh = tid >> 8;     // 0..1
            const float2 xv = *(const float2*)(X + (size_t)(r0 + r) * IN_DIM + ds + dh * 2);
            u32 rec[4];
            make_record(xv.x, rec);
            *(uint4*)(sm + W_LDS_BYTES + (((dh * 2 + 0) * 256 + r) << 4)) =
                make_uint4(rec[0], rec[1], rec[2], rec[3]);
            make_record(xv.y, rec);
            *(uint4*)(sm + W_LDS_BYTES + (((dh * 2 + 1) * 256 + r) << 4)) =
                make_uint4(rec[0], rec[1], rec[2], rec[3]);
        }
        __syncthreads();

        // ---- gather-FMA over 4 d's x 32 rows/wave ----
#pragma unroll
        for (int dl = 0; dl < D_STAGE; ++dl) {
            const int dBase = dl * D_LDS_BYTES;
            // hoist silu weight row (row 67) for this d
            uint4 wp = *(const uint4*)(sm + dBase + 67 * 128 + ((sub ^ 3) << 4));
            float w67f[8];
            w67f[0] = bflo(wp.x); w67f[1] = bfhi(wp.x);
            w67f[2] = bflo(wp.y); w67f[3] = bfhi(wp.y);
            w67f[4] = bflo(wp.z); w67f[5] = bfhi(wp.z);
            w67f[6] = bflo(wp.w); w67f[7] = bfhi(wp.w);
#pragma unroll
            for (int t = 0; t < 4; ++t) {
                uint4 rec = *(const uint4*)(sm + W_LDS_BYTES +
                                            ((dl * 256 + rb + t * 8 + g) << 4));
                const float c[4] = { bflo(rec.x), bfhi(rec.x), bflo(rec.y), bfhi(rec.y) };
                const float silu = __uint_as_float(rec.z);
                const int sbase  = (int)rec.w;
#pragma unroll
                for (int j = 0; j < 4; ++j) {
                    const int row = sbase + j;
                    uint4 wr = *(const uint4*)(sm + dBase + row * 128 +
                                               (((sub ^ (row & 7)) << 4)));
                    const float cj = c[j];
                    acc[t][0] = fmaf(cj, bflo(wr.x), acc[t][0]);
                    acc[t][1] = fmaf(cj, bfhi(wr.x), acc[t][1]);
                    acc[t][2] = fmaf(cj, bflo(wr.y), acc[t][2]);
                    acc[t][3] = fmaf(cj, bfhi(wr.y), acc[t][3]);
                    acc[t][4] = fmaf(cj, bflo(wr.z), acc[t][4]);
                    acc[t][5] = fmaf(cj, bfhi(wr.z), acc[t][5]);
                    acc[t][6] = fmaf(cj, bflo(wr.w), acc[t][6]);
                    acc[t][7] = fmaf(cj, bfhi(wr.w), acc[t][7]);
                }
#pragma unroll
                for (int k = 0; k < 8; ++k)
                    acc[t][k] = fmaf(silu, w67f[k], acc[t][k]);
            }
        }
    }

    // ---- emit partials (nontemporal: streamed once, read once by reduce) ----
    if (!useAtomic) {
        float* wsp = outbuf + (size_t)sp * (BATCH * OUT_DIM);
#pragma unroll
        for (int t = 0; t < 4; ++t) {
            const int R = r0 + rb + t * 8 + g;
            f32x4 lo = { acc[t][0], acc[t][1], acc[t][2], acc[t][3] };
            f32x4 hi = { acc[t][4], acc[t][5], acc[t][6], acc[t][7] };
            __builtin_nontemporal_store(lo, (f32x4*)(wsp + (size_t)R * 64 + sub * 8));
            __builtin_nontemporal_store(hi, (f32x4*)(wsp + (size_t)R * 64 + sub * 8 + 4));
        }
    } else {
#pragma unroll
        for (int t = 0; t < 4; ++t) {
            const int R = r0 + rb + t * 8 + g;
#pragma unroll
            for (int k = 0; k < 8; ++k)
                atomicAdd(outbuf + (size_t)R * 64 + sub * 8 + k, acc[t][k]);
        }
    }
}

__global__ __launch_bounds__(256)
void kan_reduce(const float* __restrict__ ws, float* __restrict__ out) {
    const int i = blockIdx.x * 256 + threadIdx.x;   // f32x4 index, 131072 total
    const f32x4* w4 = (const f32x4*)ws;
    f32x4 a = __builtin_nontemporal_load(&w4[i]);
#pragma unroll
    for (int s = 1; s < N_SPLIT; ++s) {
        f32x4 b = __builtin_nontemporal_load(
            &w4[(size_t)s * (BATCH * OUT_DIM / 4) + i]);
        a += b;
    }
    *(f32x4*)((float*)out + (size_t)i * 4) = a;
}

extern "C" void kernel_launch(void* const* d_in, const int* in_sizes, int n_in,
                              void* d_out, int out_size, void* d_ws, size_t ws_size,
                              hipStream_t stream) {
    const float* X = (const float*)d_in[0];
    const float* W = (const float*)d_in[1];
    float* out = (float*)d_out;
    const size_t need = (size_t)N_SPLIT * BATCH * OUT_DIM * sizeof(float);
    dim3 grid(NM, N_SPLIT);
    if (ws_size >= need) {
        kan_main<<<grid, 512, 0, stream>>>(X, W, (float*)d_ws, 0);
        kan_reduce<<<(BATCH * OUT_DIM / 4) / 256, 256, 0, stream>>>((const float*)d_ws, out);
    } else {
        (void)hipMemsetAsync(d_out, 0, (size_t)out_size * sizeof(float), stream);
        kan_main<<<grid, 512, 0, stream>>>(X, W, out, 1);
    }
}

// Round 4
// 73.601 us; speedup vs baseline: 2.1619x; 1.1419x over previous
//
#include <hip/hip_runtime.h>
#include <stdint.h>

// Problem constants (from reference)
#define BATCH   8192
#define IN_DIM  256
#define OUT_DIM 64
#define NROW    68      // 67 spline bases + 1 silu row per d
#define N_SPLIT 16      // d-splits
#define D_SLICE 16      // d's per block (256/N_SPLIT)
#define D_STAGE 2       // d's staged in LDS at once (pair table is 2x bytes)
#define N_STAGE 8       // stages per block
#define M_BLK   128     // batch rows per block
#define NM      64      // 8192/M_BLK

typedef unsigned int u32;
typedef float f32x4 __attribute__((ext_vector_type(4)));
typedef __bf16 bf16x2 __attribute__((ext_vector_type(2)));

#if defined(__has_builtin)
#  if __has_builtin(__builtin_amdgcn_fdot2_f32_bf16)
#    define HAVE_DOT2 1
#  endif
#endif
#ifndef HAVE_DOT2
#  define HAVE_DOT2 0
#endif

__device__ __forceinline__ u32 f2bf(float f) {              // f32 -> bf16 (RNE)
    u32 u = __float_as_uint(f);
    u += 0x7FFFu + ((u >> 16) & 1u);
    return u >> 16;
}
__device__ __forceinline__ float bflo(u32 u) { return __uint_as_float(u << 16); }
__device__ __forceinline__ float bfhi(u32 u) { return __uint_as_float(u & 0xFFFF0000u); }

// a, b are bf16x2 packed in u32 (element0 = low 16 bits). Returns
// a0*b0 + a1*b1 + c.  v_dot2_f32_bf16 if available, scalar fallback else.
__device__ __forceinline__ float dot2bf(u32 a, u32 b, float c) {
#if HAVE_DOT2
    bf16x2 av, bv;
    __builtin_memcpy(&av, &a, 4);
    __builtin_memcpy(&bv, &b, 4);
    return __builtin_amdgcn_fdot2_f32_bf16(av, bv, c, false);
#else
    return fmaf(bflo(a), bflo(b), fmaf(bfhi(a), bfhi(b), c));
#endif
}

// knot t[i], i in [0,70]: 3 clamped zeros, linspace(0,1,65), 3 clamped ones.
__device__ __forceinline__ float knotf(int i) {
    return fminf(1.f, fmaxf(0.f, (float)(i - 3) * 0.015625f));
}

// Windowed Cox-de Boor (degree 3). Record: {c0|c1, c2|c3 (bf16x2), silu f32, s}
__device__ __forceinline__ void make_record(float x, u32 rec[4]) {
    int s = (int)floorf(x * 64.f);
    s = max(0, min(63, s));
    const int m = s + 3;
    float N0 = 1.f, N1, N2, N3;
    const float l1 = x - knotf(m);
    const float r1 = knotf(m + 1) - x;
    {
        float tmp = N0 / (r1 + l1);
        N0 = r1 * tmp;
        N1 = l1 * tmp;
    }
    const float l2 = x - knotf(m - 1);
    const float r2 = knotf(m + 2) - x;
    {
        float tmp = N0 / (r1 + l2);
        N0 = r1 * tmp;
        float saved = l2 * tmp;
        tmp = N1 / (r2 + l1);
        N1 = saved + r2 * tmp;
        N2 = l1 * tmp;
    }
    const float l3 = x - knotf(m - 2);
    const float r3 = knotf(m + 3) - x;
    {
        float tmp = N0 / (r1 + l3);
        N0 = r1 * tmp;
        float saved = l3 * tmp;
        tmp = N1 / (r2 + l2);
        N1 = saved + r2 * tmp;
        saved = l2 * tmp;
        tmp = N2 / (r3 + l1);
        N2 = saved + r3 * tmp;
        N3 = l1 * tmp;
    }
    const float silu = x / (1.f + __expf(-x));
    rec[0] = f2bf(N0) | (f2bf(N1) << 16);
    rec[1] = f2bf(N2) | (f2bf(N3) << 16);
    rec[2] = __float_as_uint(silu);
    rec[3] = (u32)s;
}

// LDS layout (38656 B):
//   [0, 34304):        pair tables, 2 d's: per d 67 rows x 64 bf16x2 dwords,
//                      row stride 256 B; 32B-chunk XOR swizzle: chunk = (o>>3)^(r&7)
//                      wpair[d][r][o] = { w[r][o], w[r+1][o] }
//   [34304, 34560):    silu rows (row 67), 2 d x 64 bf16
//   [34560, 38656):    coeff records [2 dl][128 r] x 16 B
#define TAB_D     17152
#define SILU_OFF  34304
#define REC_OFF   34560
#define LDS_U4    2416

// 256-thread blocks, 4 blocks/CU target. VGPR cap 512/4 = 128 (R1 lesson:
// never cap below static demand; hot-loop live set ~80 here).
__global__ __launch_bounds__(256, 4)
void kan_main(const float* __restrict__ X, const float* __restrict__ W,
              float* __restrict__ outbuf, int useAtomic) {
    __shared__ uint4 smem4[LDS_U4];
    char* sm = (char*)smem4;

    const int mb  = blockIdx.x;          // 0..63
    const int sp  = blockIdx.y;          // 0..15
    const int tid = threadIdx.x;
    const int r0  = mb * M_BLK;
    const int d0  = sp * D_SLICE;

    const int lane = tid & 63;
    const int wv   = tid >> 6;           // wave 0..3
    const int sub  = lane & 7;           // o-chunk (8 outputs)
    const int g    = lane >> 3;          // row-in-round 0..7
    const int rb   = wv * 32;            // wave's local row base

    float acc[4][8];
#pragma unroll
    for (int t = 0; t < 4; ++t)
#pragma unroll
        for (int k = 0; k < 8; ++k) acc[t][k] = 0.f;

    for (int st = 0; st < N_STAGE; ++st) {
        const int ds = d0 + st * D_STAGE;
        __syncthreads();   // prev stage's readers done before overwrite

        // ---- stage pair table: 2 d x 67 rowpairs x 16 b128 entries ----
        {
            const float* wbase = W + (size_t)ds * (NROW * OUT_DIM);
            for (int i = tid; i < 2 * 67 * 16; i += 256) {
                const int dl  = (i >= 1072) ? 1 : 0;
                const int rem = i - dl * 1072;
                const int r   = rem >> 4;
                const int c16 = rem & 15;          // 4-output group in row
                const float* p = wbase + (size_t)dl * (NROW * OUT_DIM)
                               + r * OUT_DIM + (c16 << 2);
                float4 va = *(const float4*)p;             // row r
                float4 vb = *(const float4*)(p + OUT_DIM); // row r+1
                u32 e0 = f2bf(va.x) | (f2bf(vb.x) << 16);
                u32 e1 = f2bf(va.y) | (f2bf(vb.y) << 16);
                u32 e2 = f2bf(va.z) | (f2bf(vb.z) << 16);
                u32 e3 = f2bf(va.w) | (f2bf(vb.w) << 16);
                const int byte = dl * TAB_D + r * 256
                               + (((c16 >> 1) ^ (r & 7)) << 5) + ((c16 & 1) << 4);
                *(uint4*)(sm + byte) = make_uint4(e0, e1, e2, e3);
            }
            // silu rows (row 67): 64 threads x 1 dword
            if (tid < 64) {
                const int dl = tid >> 5, j = tid & 31;
                const float* p = wbase + (size_t)dl * (NROW * OUT_DIM)
                               + 67 * OUT_DIM + j * 2;
                *(u32*)(sm + SILU_OFF + dl * 128 + j * 4) =
                    f2bf(p[0]) | (f2bf(p[1]) << 16);
            }
        }
        // ---- coeff records: 128 rows x 2 d, one per thread ----
        {
            const int r  = tid & 127;
            const int dh = tid >> 7;     // 0..1
            const float x = X[(size_t)(r0 + r) * IN_DIM + ds + dh];
            u32 rec[4];
            make_record(x, rec);
            *(uint4*)(sm + REC_OFF + ((dh * 128 + r) << 4)) =
                make_uint4(rec[0], rec[1], rec[2], rec[3]);
        }
        __syncthreads();

        // ---- gather + dot2 over 2 d's x 32 rows/wave ----
#pragma unroll
        for (int dl = 0; dl < D_STAGE; ++dl) {
            const int tb = dl * TAB_D;
            // hoist silu weight row for this d (broadcast within g-groups)
            uint4 wp = *(const uint4*)(sm + SILU_OFF + dl * 128 + sub * 16);
            float w67f[8];
            w67f[0] = bflo(wp.x); w67f[1] = bfhi(wp.x);
            w67f[2] = bflo(wp.y); w67f[3] = bfhi(wp.y);
            w67f[4] = bflo(wp.z); w67f[5] = bfhi(wp.z);
            w67f[6] = bflo(wp.w); w67f[7] = bfhi(wp.w);
#pragma unroll
            for (int t = 0; t < 4; ++t) {
                const uint4 rec = *(const uint4*)(sm + REC_OFF +
                                                  ((dl * 128 + rb + t * 8 + g) << 4));
                const u32 c01 = rec.x, c23 = rec.y;
                const float silu = __uint_as_float(rec.z);
                const int s = (int)rec.w;
                const char* a1 = sm + tb + s * 256 + (((sub ^ s) & 7) << 5);
                const char* a2 = sm + tb + (s + 2) * 256 + (((sub ^ (s + 2)) & 7) << 5);
                const uint4 p1  = *(const uint4*)(a1);        // pairs (s,s+1), o 0..3
                const uint4 p1b = *(const uint4*)(a1 + 16);   // o 4..7
                const uint4 p2  = *(const uint4*)(a2);        // pairs (s+2,s+3)
                const uint4 p2b = *(const uint4*)(a2 + 16);
                acc[t][0] = dot2bf(c23, p2.x,  dot2bf(c01, p1.x,  acc[t][0]));
                acc[t][1] = dot2bf(c23, p2.y,  dot2bf(c01, p1.y,  acc[t][1]));
                acc[t][2] = dot2bf(c23, p2.z,  dot2bf(c01, p1.z,  acc[t][2]));
                acc[t][3] = dot2bf(c23, p2.w,  dot2bf(c01, p1.w,  acc[t][3]));
                acc[t][4] = dot2bf(c23, p2b.x, dot2bf(c01, p1b.x, acc[t][4]));
                acc[t][5] = dot2bf(c23, p2b.y, dot2bf(c01, p1b.y, acc[t][5]));
                acc[t][6] = dot2bf(c23, p2b.z, dot2bf(c01, p1b.z, acc[t][6]));
                acc[t][7] = dot2bf(c23, p2b.w, dot2bf(c01, p1b.w, acc[t][7]));
#pragma unroll
                for (int k = 0; k < 8; ++k)
                    acc[t][k] = fmaf(silu, w67f[k], acc[t][k]);
            }
        }
    }

    // ---- emit partials (nontemporal: streamed once, read once by reduce) ----
    if (!useAtomic) {
        float* wsp = outbuf + (size_t)sp * (BATCH * OUT_DIM);
#pragma unroll
        for (int t = 0; t < 4; ++t) {
            const int R = r0 + rb + t * 8 + g;
            f32x4 lo = { acc[t][0], acc[t][1], acc[t][2], acc[t][3] };
            f32x4 hi = { acc[t][4], acc[t][5], acc[t][6], acc[t][7] };
            __builtin_nontemporal_store(lo, (f32x4*)(wsp + (size_t)R * 64 + sub * 8));
            __builtin_nontemporal_store(hi, (f32x4*)(wsp + (size_t)R * 64 + sub * 8 + 4));
        }
    } else {
#pragma unroll
        for (int t = 0; t < 4; ++t) {
            const int R = r0 + rb + t * 8 + g;
#pragma unroll
            for (int k = 0; k < 8; ++k)
                atomicAdd(outbuf + (size_t)R * 64 + sub * 8 + k, acc[t][k]);
        }
    }
}

__global__ __launch_bounds__(256)
void kan_reduce(const float* __restrict__ ws, float* __restrict__ out) {
    const int i = blockIdx.x * 256 + threadIdx.x;   // f32x4 index, 131072 total
    const f32x4* w4 = (const f32x4*)ws;
    f32x4 a = __builtin_nontemporal_load(&w4[i]);
#pragma unroll
    for (int s = 1; s < N_SPLIT; ++s) {
        f32x4 b = __builtin_nontemporal_load(
            &w4[(size_t)s * (BATCH * OUT_DIM / 4) + i]);
        a += b;
    }
    *(f32x4*)((float*)out + (size_t)i * 4) = a;
}

extern "C" void kernel_launch(void* const* d_in, const int* in_sizes, int n_in,
                              void* d_out, int out_size, void* d_ws, size_t ws_size,
                              hipStream_t stream) {
    const float* X = (const float*)d_in[0];
    const float* W = (const float*)d_in[1];
    float* out = (float*)d_out;
    const size_t need = (size_t)N_SPLIT * BATCH * OUT_DIM * sizeof(float);
    dim3 grid(NM, N_SPLIT);
    if (ws_size >= need) {
        kan_main<<<grid, 256, 0, stream>>>(X, W, (float*)d_ws, 0);
        kan_reduce<<<(BATCH * OUT_DIM / 4) / 256, 256, 0, stream>>>((const float*)d_ws, out);
    } else {
        (void)hipMemsetAsync(d_out, 0, (size_t)out_size * sizeof(float), stream);
        kan_main<<<grid, 256, 0, stream>>>(X, W, out, 1);
    }
}

// Round 5
// 60.576 us; speedup vs baseline: 2.6268x; 1.2150x over previous
//
#include <hip/hip_runtime.h>
#include <stdint.h>

// Problem constants (from reference)
#define BATCH   8192
#define IN_DIM  256
#define OUT_DIM 64
#define NROW    68      // 67 spline rows + 1 silu row per d
#define N_SPLIT 16      // d-splits
#define D_SLICE 16      // d's per block (256/N_SPLIT)
#define D_STAGE 2       // d's staged in LDS at once
#define N_STAGE 8       // stages per block
#define M_BLK   256     // batch rows per block
#define NM      32      // 8192/M_BLK

typedef unsigned int u32;
typedef float f32x4 __attribute__((ext_vector_type(4)));
typedef __bf16 bf16x2 __attribute__((ext_vector_type(2)));

#if defined(__has_builtin)
#  if __has_builtin(__builtin_amdgcn_fdot2_f32_bf16)
#    define HAVE_DOT2 1
#  endif
#endif
#ifndef HAVE_DOT2
#  define HAVE_DOT2 0
#endif

__device__ __forceinline__ u32 f2bf(float f) {              // f32 -> bf16 (RNE)
    u32 u = __float_as_uint(f);
    u += 0x7FFFu + ((u >> 16) & 1u);
    return u >> 16;
}
__device__ __forceinline__ float bflo(u32 u) { return __uint_as_float(u << 16); }
__device__ __forceinline__ float bfhi(u32 u) { return __uint_as_float(u & 0xFFFF0000u); }

// {lo, hi} f32 pair -> packed bf16x2 dword via HW v_cvt_pk_bf16_f32
// (compiler emits it from scalar casts; m240: don't hand-write the asm).
__device__ __forceinline__ u32 pkbf(float lo, float hi) {
    bf16x2 v = { (__bf16)lo, (__bf16)hi };
    u32 u;
    __builtin_memcpy(&u, &v, 4);
    return u;
}

// a, b are bf16x2 packed in u32 (element0 = low 16 bits): a0*b0 + a1*b1 + c
__device__ __forceinline__ float dot2bf(u32 a, u32 b, float c) {
#if HAVE_DOT2
    bf16x2 av, bv;
    __builtin_memcpy(&av, &a, 4);
    __builtin_memcpy(&bv, &b, 4);
    return __builtin_amdgcn_fdot2_f32_bf16(av, bv, c, false);
#else
    return fmaf(bflo(a), bflo(b), fmaf(bfhi(a), bfhi(b), c));
#endif
}

// knot t[i], i in [0,70]: 3 clamped zeros, linspace(0,1,65), 3 clamped ones.
__device__ __forceinline__ float knotf(int i) {
    return fminf(1.f, fmaxf(0.f, (float)(i - 3) * 0.015625f));
}

// Windowed Cox-de Boor (degree 3). Record: {c0|c1, c2|c3 (bf16x2), silu f32, s}
__device__ __forceinline__ void make_record(float x, u32 rec[4]) {
    int s = (int)floorf(x * 64.f);
    s = max(0, min(63, s));
    const int m = s + 3;
    float N0 = 1.f, N1, N2, N3;
    const float l1 = x - knotf(m);
    const float r1 = knotf(m + 1) - x;
    {
        float tmp = N0 / (r1 + l1);
        N0 = r1 * tmp;
        N1 = l1 * tmp;
    }
    const float l2 = x - knotf(m - 1);
    const float r2 = knotf(m + 2) - x;
    {
        float tmp = N0 / (r1 + l2);
        N0 = r1 * tmp;
        float saved = l2 * tmp;
        tmp = N1 / (r2 + l1);
        N1 = saved + r2 * tmp;
        N2 = l1 * tmp;
    }
    const float l3 = x - knotf(m - 2);
    const float r3 = knotf(m + 3) - x;
    {
        float tmp = N0 / (r1 + l3);
        N0 = r1 * tmp;
        float saved = l3 * tmp;
        tmp = N1 / (r2 + l2);
        N1 = saved + r2 * tmp;
        saved = l2 * tmp;
        tmp = N2 / (r3 + l1);
        N2 = saved + r3 * tmp;
        N3 = l1 * tmp;
    }
    const float silu = x / (1.f + __expf(-x));
    rec[0] = f2bf(N0) | (f2bf(N1) << 16);
    rec[1] = f2bf(N2) | (f2bf(N3) << 16);
    rec[2] = __float_as_uint(silu);
    rec[3] = (u32)s;
}

// LDS layout (42240 B):
//   [0, 33792):        pair tables, 2 d's: per d 66 pair-rows x 64 bf16x2,
//                      row stride 256 B; 32B-chunk XOR swizzle ((c16>>1)^(r&7))
//                      wpair[d][r][o] = { w[r][o], w[r+1][o] },  r = 0..65
//   [33792, 34048):    silu rows (w row 67), 2 d x 64 bf16
//   [34048, 42240):    coeff records [2 dl][256 r] x 16 B
#define TAB_D     16896
#define SILU_OFF  33792
#define REC_OFF   34048
#define LDS_U4    2640

__global__ __launch_bounds__(512, 3)
void kan_main(const float* __restrict__ X, const float* __restrict__ W,
              float* __restrict__ outbuf, int useAtomic) {
    __shared__ uint4 smem4[LDS_U4];
    char* sm = (char*)smem4;

    const int mb  = blockIdx.x;          // 0..31
    const int sp  = blockIdx.y;          // 0..15
    const int tid = threadIdx.x;
    const int r0  = mb * M_BLK;
    const int d0  = sp * D_SLICE;

    const int lane = tid & 63;
    const int wv   = tid >> 6;           // wave 0..7
    const int sub  = lane & 7;           // o-chunk (8 outputs)
    const int g    = lane >> 3;          // row-in-round 0..7
    const int rb   = wv * 32;            // wave's local row base

    float acc[4][8];
#pragma unroll
    for (int t = 0; t < 4; ++t)
#pragma unroll
        for (int k = 0; k < 8; ++k) acc[t][k] = 0.f;

    for (int st = 0; st < N_STAGE; ++st) {
        const int ds = d0 + st * D_STAGE;
        __syncthreads();   // prev stage's readers done before overwrite

        // ---- stage pair table: 2 d x 66 pair-rows x 16 uint4 entries ----
        {
            const float* wbase = W + (size_t)ds * (NROW * OUT_DIM);
            for (int i = tid; i < 2 * 66 * 16; i += 512) {
                const int dl  = (i >= 1056) ? 1 : 0;
                const int rem = i - dl * 1056;
                const int r   = rem >> 4;
                const int c16 = rem & 15;          // 4-output group in row
                const float* p = wbase + (size_t)dl * (NROW * OUT_DIM)
                               + r * OUT_DIM + (c16 << 2);
                float4 va = *(const float4*)p;             // row r
                float4 vb = *(const float4*)(p + OUT_DIM); // row r+1
                const int byte = dl * TAB_D + r * 256
                               + (((c16 >> 1) ^ (r & 7)) << 5) + ((c16 & 1) << 4);
                *(uint4*)(sm + byte) = make_uint4(pkbf(va.x, vb.x), pkbf(va.y, vb.y),
                                                  pkbf(va.z, vb.z), pkbf(va.w, vb.w));
            }
            // silu rows (w row 67): tail 64 threads (balance vs 4-iter loop above)
            if (tid >= 448) {
                int j = tid - 448;                 // 0..63
                const int dl = j >> 5; j &= 31;
                const float* p = wbase + (size_t)dl * (NROW * OUT_DIM)
                               + 67 * OUT_DIM + j * 2;
                *(u32*)(sm + SILU_OFF + dl * 128 + j * 4) = pkbf(p[0], p[1]);
            }
        }
        // ---- coeff records: 256 rows x 2 d, one per thread ----
        {
            const int r  = tid & 255;
            const int dh = tid >> 8;     // 0..1
            const float x = X[(size_t)(r0 + r) * IN_DIM + ds + dh];
            u32 rec[4];
            make_record(x, rec);
            *(uint4*)(sm + REC_OFF + ((dh * 256 + r) << 4)) =
                make_uint4(rec[0], rec[1], rec[2], rec[3]);
        }
        __syncthreads();

        // ---- gather + dot2 over 2 d's x 32 rows/wave ----
#pragma unroll
        for (int dl = 0; dl < D_STAGE; ++dl) {
            const int tb = dl * TAB_D;
            uint4 wp = *(const uint4*)(sm + SILU_OFF + dl * 128 + sub * 16);
            float w67f[8];
            w67f[0] = bflo(wp.x); w67f[1] = bfhi(wp.x);
            w67f[2] = bflo(wp.y); w67f[3] = bfhi(wp.y);
            w67f[4] = bflo(wp.z); w67f[5] = bfhi(wp.z);
            w67f[6] = bflo(wp.w); w67f[7] = bfhi(wp.w);
#pragma unroll
            for (int t = 0; t < 4; ++t) {
                const uint4 rec = *(const uint4*)(sm + REC_OFF +
                                                  ((dl * 256 + rb + t * 8 + g) << 4));
                const u32 c01 = rec.x, c23 = rec.y;
                const float silu = __uint_as_float(rec.z);
                const int s = (int)rec.w;
                const char* a1 = sm + tb + s * 256 + (((sub ^ s) & 7) << 5);
                const char* a2 = sm + tb + (s + 2) * 256 + (((sub ^ (s + 2)) & 7) << 5);
                const uint4 p1  = *(const uint4*)(a1);        // pairs (s,s+1), o 0..3
                const uint4 p1b = *(const uint4*)(a1 + 16);   // o 4..7
                const uint4 p2  = *(const uint4*)(a2);        // pairs (s+2,s+3)
                const uint4 p2b = *(const uint4*)(a2 + 16);
                acc[t][0] = dot2bf(c23, p2.x,  dot2bf(c01, p1.x,  acc[t][0]));
                acc[t][1] = dot2bf(c23, p2.y,  dot2bf(c01, p1.y,  acc[t][1]));
                acc[t][2] = dot2bf(c23, p2.z,  dot2bf(c01, p1.z,  acc[t][2]));
                acc[t][3] = dot2bf(c23, p2.w,  dot2bf(c01, p1.w,  acc[t][3]));
                acc[t][4] = dot2bf(c23, p2b.x, dot2bf(c01, p1b.x, acc[t][4]));
                acc[t][5] = dot2bf(c23, p2b.y, dot2bf(c01, p1b.y, acc[t][5]));
                acc[t][6] = dot2bf(c23, p2b.z, dot2bf(c01, p1b.z, acc[t][6]));
                acc[t][7] = dot2bf(c23, p2b.w, dot2bf(c01, p1b.w, acc[t][7]));
#pragma unroll
                for (int k = 0; k < 8; ++k)
                    acc[t][k] = fmaf(silu, w67f[k], acc[t][k]);
            }
        }
    }

    // ---- emit partials (nontemporal: streamed once, read once by reduce) ----
    if (!useAtomic) {
        float* wsp = outbuf + (size_t)sp * (BATCH * OUT_DIM);
#pragma unroll
        for (int t = 0; t < 4; ++t) {
            const int R = r0 + rb + t * 8 + g;
            f32x4 lo = { acc[t][0], acc[t][1], acc[t][2], acc[t][3] };
            f32x4 hi = { acc[t][4], acc[t][5], acc[t][6], acc[t][7] };
            __builtin_nontemporal_store(lo, (f32x4*)(wsp + (size_t)R * 64 + sub * 8));
            __builtin_nontemporal_store(hi, (f32x4*)(wsp + (size_t)R * 64 + sub * 8 + 4));
        }
    } else {
#pragma unroll
        for (int t = 0; t < 4; ++t) {
            const int R = r0 + rb + t * 8 + g;
#pragma unroll
            for (int k = 0; k < 8; ++k)
                atomicAdd(outbuf + (size_t)R * 64 + sub * 8 + k, acc[t][k]);
        }
    }
}

__global__ __launch_bounds__(256)
void kan_reduce(const float* __restrict__ ws, float* __restrict__ out) {
    const int i = blockIdx.x * 256 + threadIdx.x;   // f32x4 index, 131072 total
    const f32x4* w4 = (const f32x4*)ws;
    f32x4 a = __builtin_nontemporal_load(&w4[i]);
#pragma unroll
    for (int s = 1; s < N_SPLIT; ++s) {
        f32x4 b = __builtin_nontemporal_load(
            &w4[(size_t)s * (BATCH * OUT_DIM / 4) + i]);
        a += b;
    }
    *(f32x4*)((float*)out + (size_t)i * 4) = a;
}

extern "C" void kernel_launch(void* const* d_in, const int* in_sizes, int n_in,
                              void* d_out, int out_size, void* d_ws, size_t ws_size,
                              hipStream_t stream) {
    const float* X = (const float*)d_in[0];
    const float* W = (const float*)d_in[1];
    float* out = (float*)d_out;
    const size_t need = (size_t)N_SPLIT * BATCH * OUT_DIM * sizeof(float);
    dim3 grid(NM, N_SPLIT);
    if (ws_size >= need) {
        kan_main<<<grid, 512, 0, stream>>>(X, W, (float*)d_ws, 0);
        kan_reduce<<<(BATCH * OUT_DIM / 4) / 256, 256, 0, stream>>>((const float*)d_ws, out);
    } else {
        (void)hipMemsetAsync(d_out, 0, (size_t)out_size * sizeof(float), stream);
        kan_main<<<grid, 512, 0, stream>>>(X, W, out, 1);
    }
}

// Round 6
// 49.258 us; speedup vs baseline: 3.2303x; 1.2298x over previous
//
#include <hip/hip_runtime.h>
#include <stdint.h>

// Problem constants (from reference)
#define BATCH   8192
#define IN_DIM  256
#define OUT_DIM 64
#define NROW    68      // 67 spline rows + 1 silu row per d
#define N_SPLIT 16      // d-splits
#define D_SLICE 16      // d's per block (256/N_SPLIT)
#define D_STAGE 2       // d's staged in LDS at once
#define N_STAGE 8       // stages per block
#define M_BLK   256     // batch rows per block
#define NM      32      // 8192/M_BLK

typedef unsigned int u32;
typedef float f32x4 __attribute__((ext_vector_type(4)));
typedef u32   u32x2 __attribute__((ext_vector_type(2)));
typedef __bf16 bf16x2 __attribute__((ext_vector_type(2)));

#if defined(__has_builtin)
#  if __has_builtin(__builtin_amdgcn_fdot2_f32_bf16)
#    define HAVE_DOT2 1
#  endif
#endif
#ifndef HAVE_DOT2
#  define HAVE_DOT2 0
#endif

__device__ __forceinline__ u32 f2bf(float f) {              // f32 -> bf16 (RNE)
    u32 u = __float_as_uint(f);
    u += 0x7FFFu + ((u >> 16) & 1u);
    return u >> 16;
}
__device__ __forceinline__ float bflo(u32 u) { return __uint_as_float(u << 16); }
__device__ __forceinline__ float bfhi(u32 u) { return __uint_as_float(u & 0xFFFF0000u); }

// {lo, hi} f32 pair -> packed bf16x2 dword (HW v_cvt_pk_bf16_f32 via casts)
__device__ __forceinline__ u32 pkbf(float lo, float hi) {
    bf16x2 v = { (__bf16)lo, (__bf16)hi };
    u32 u;
    __builtin_memcpy(&u, &v, 4);
    return u;
}

// a, b are bf16x2 packed in u32 (element0 = low 16 bits): a0*b0 + a1*b1 + c
__device__ __forceinline__ float dot2bf(u32 a, u32 b, float c) {
#if HAVE_DOT2
    bf16x2 av, bv;
    __builtin_memcpy(&av, &a, 4);
    __builtin_memcpy(&bv, &b, 4);
    return __builtin_amdgcn_fdot2_f32_bf16(av, bv, c, false);
#else
    return fmaf(bflo(a), bflo(b), fmaf(bfhi(a), bfhi(b), c));
#endif
}

// knot t[i], i in [0,70]: 3 clamped zeros, linspace(0,1,65), 3 clamped ones.
__device__ __forceinline__ float knotf(int i) {
    return fminf(1.f, fmaxf(0.f, (float)(i - 3) * 0.015625f));
}

// Windowed Cox-de Boor (degree 3). Record: {c0|c1, c2|c3 (bf16x2), silu f32, s}
__device__ __forceinline__ void make_record(float x, u32 rec[4]) {
    int s = (int)floorf(x * 64.f);
    s = max(0, min(63, s));
    const int m = s + 3;
    float N0 = 1.f, N1, N2, N3;
    const float l1 = x - knotf(m);
    const float r1 = knotf(m + 1) - x;
    {
        float tmp = N0 / (r1 + l1);
        N0 = r1 * tmp;
        N1 = l1 * tmp;
    }
    const float l2 = x - knotf(m - 1);
    const float r2 = knotf(m + 2) - x;
    {
        float tmp = N0 / (r1 + l2);
        N0 = r1 * tmp;
        float saved = l2 * tmp;
        tmp = N1 / (r2 + l1);
        N1 = saved + r2 * tmp;
        N2 = l1 * tmp;
    }
    const float l3 = x - knotf(m - 2);
    const float r3 = knotf(m + 3) - x;
    {
        float tmp = N0 / (r1 + l3);
        N0 = r1 * tmp;
        float saved = l3 * tmp;
        tmp = N1 / (r2 + l2);
        N1 = saved + r2 * tmp;
        saved = l2 * tmp;
        tmp = N2 / (r3 + l1);
        N2 = saved + r3 * tmp;
        N3 = l1 * tmp;
    }
    const float silu = x / (1.f + __expf(-x));
    rec[0] = f2bf(N0) | (f2bf(N1) << 16);
    rec[1] = f2bf(N2) | (f2bf(N3) << 16);
    rec[2] = __float_as_uint(silu);
    rec[3] = (u32)s;
}

// LDS layout (42496 B), all LINEAR (conflict-freedom is structural: every
// 8-lane octet of a gather read covers one contiguous 128-B bank stripe):
//   [0, 33792):        pair tables, 2 d's: per d 66 pair-rows x 64 bf16x2,
//                      row stride 256 B. wpair[d][r][o] = {w[r][o], w[r+1][o]}
//   [33792, 34304):    silu rows (w row 67) as f32[64] per d (2 x 256 B)
//   [34304, 42496):    coeff records [2 dl][256 r] x 16 B
#define TAB_D     16896
#define SILU_OFF  33792
#define REC_OFF   34304
#define LDS_U4    2656

__global__ __launch_bounds__(512, 3)
void kan_main(const float* __restrict__ X, const float* __restrict__ W,
              void* __restrict__ outbuf, int useAtomic) {
    __shared__ uint4 smem4[LDS_U4];
    char* sm = (char*)smem4;

    const int mb  = blockIdx.x;          // 0..31
    const int sp  = blockIdx.y;          // 0..15
    const int tid = threadIdx.x;
    const int r0  = mb * M_BLK;
    const int d0  = sp * D_SLICE;

    const int lane = tid & 63;
    const int wv   = tid >> 6;           // wave 0..7
    const int sub  = lane & 7;           // output-chunk selector
    const int g    = lane >> 3;          // row-in-round 0..7
    const int rb   = wv * 32;            // wave's local row base

    // lane covers outputs {sub*4..+3} and {32+sub*4..+3}
    float acc[4][8];
#pragma unroll
    for (int t = 0; t < 4; ++t)
#pragma unroll
        for (int k = 0; k < 8; ++k) acc[t][k] = 0.f;

    for (int st = 0; st < N_STAGE; ++st) {
        const int ds = d0 + st * D_STAGE;
        __syncthreads();   // prev stage's readers done before overwrite

        // ---- stage pair table: 2 d x 66 pair-rows x 16 uint4, linear ----
        {
            const float* wbase = W + (size_t)ds * (NROW * OUT_DIM);
            for (int i = tid; i < 2 * 66 * 16; i += 512) {
                const int dl  = (i >= 1056) ? 1 : 0;
                const int rem = i - dl * 1056;
                const int r   = rem >> 4;
                const int c16 = rem & 15;          // 16-B chunk in row (4 outputs)
                const float* p = wbase + (size_t)dl * (NROW * OUT_DIM)
                               + r * OUT_DIM + (c16 << 2);
                float4 va = *(const float4*)p;             // row r
                float4 vb = *(const float4*)(p + OUT_DIM); // row r+1
                const int byte = dl * TAB_D + r * 256 + (c16 << 4);
                *(uint4*)(sm + byte) = make_uint4(pkbf(va.x, vb.x), pkbf(va.y, vb.y),
                                                  pkbf(va.z, vb.z), pkbf(va.w, vb.w));
            }
            // silu rows (w row 67) as f32: tail 64 threads, 2 d's each
            if (tid >= 448) {
                const int j = tid - 448;           // 0..63
#pragma unroll
                for (int dl = 0; dl < 2; ++dl) {
                    *(float*)(sm + SILU_OFF + dl * 256 + j * 4) =
                        wbase[(size_t)dl * (NROW * OUT_DIM) + 67 * OUT_DIM + j];
                }
            }
        }
        // ---- coeff records: 256 rows x 2 d, one per thread ----
        {
            const int r  = tid & 255;
            const int dh = tid >> 8;     // 0..1
            const float x = X[(size_t)(r0 + r) * IN_DIM + ds + dh];
            u32 rec[4];
            make_record(x, rec);
            *(uint4*)(sm + REC_OFF + ((dh * 256 + r) << 4)) =
                make_uint4(rec[0], rec[1], rec[2], rec[3]);
        }
        __syncthreads();

        // ---- gather + dot2 over 2 d's x 32 rows/wave ----
#pragma unroll
        for (int dl = 0; dl < D_STAGE; ++dl) {
            const int tb = dl * TAB_D;
            // silu weight row, f32, two conflict-free stripes
            const f32x4 w67a = *(const f32x4*)(sm + SILU_OFF + dl * 256 + sub * 16);
            const f32x4 w67b = *(const f32x4*)(sm + SILU_OFF + dl * 256 + 128 + sub * 16);
#pragma unroll
            for (int t = 0; t < 4; ++t) {
                const uint4 rec = *(const uint4*)(sm + REC_OFF +
                                                  ((dl * 256 + rb + t * 8 + g) << 4));
                const u32 c01 = rec.x, c23 = rec.y;
                const float silu = __uint_as_float(rec.z);
                const int s = (int)rec.w;
                const char* r1 = sm + tb + s * 256 + sub * 16;        // pair-row s
                const char* r2 = sm + tb + (s + 2) * 256 + sub * 16;  // pair-row s+2
                const uint4 p1  = *(const uint4*)(r1);          // outputs sub*4..+3
                const uint4 p1b = *(const uint4*)(r1 + 128);    // outputs 32+sub*4..+3
                const uint4 p2  = *(const uint4*)(r2);
                const uint4 p2b = *(const uint4*)(r2 + 128);
                acc[t][0] = dot2bf(c23, p2.x,  dot2bf(c01, p1.x,  acc[t][0]));
                acc[t][1] = dot2bf(c23, p2.y,  dot2bf(c01, p1.y,  acc[t][1]));
                acc[t][2] = dot2bf(c23, p2.z,  dot2bf(c01, p1.z,  acc[t][2]));
                acc[t][3] = dot2bf(c23, p2.w,  dot2bf(c01, p1.w,  acc[t][3]));
                acc[t][4] = dot2bf(c23, p2b.x, dot2bf(c01, p1b.x, acc[t][4]));
                acc[t][5] = dot2bf(c23, p2b.y, dot2bf(c01, p1b.y, acc[t][5]));
                acc[t][6] = dot2bf(c23, p2b.z, dot2bf(c01, p1b.z, acc[t][6]));
                acc[t][7] = dot2bf(c23, p2b.w, dot2bf(c01, p1b.w, acc[t][7]));
                acc[t][0] = fmaf(silu, w67a.x, acc[t][0]);
                acc[t][1] = fmaf(silu, w67a.y, acc[t][1]);
                acc[t][2] = fmaf(silu, w67a.z, acc[t][2]);
                acc[t][3] = fmaf(silu, w67a.w, acc[t][3]);
                acc[t][4] = fmaf(silu, w67b.x, acc[t][4]);
                acc[t][5] = fmaf(silu, w67b.y, acc[t][5]);
                acc[t][6] = fmaf(silu, w67b.z, acc[t][6]);
                acc[t][7] = fmaf(silu, w67b.w, acc[t][7]);
            }
        }
    }

    // ---- emit partials as bf16 planes (streamed once, read once) ----
    if (!useAtomic) {
        char* wsp = (char*)outbuf + (size_t)sp * (BATCH * OUT_DIM * 2);
#pragma unroll
        for (int t = 0; t < 4; ++t) {
            const int R = r0 + rb + t * 8 + g;
            u32x2 lo = { pkbf(acc[t][0], acc[t][1]), pkbf(acc[t][2], acc[t][3]) };
            u32x2 hi = { pkbf(acc[t][4], acc[t][5]), pkbf(acc[t][6], acc[t][7]) };
            __builtin_nontemporal_store(lo, (u32x2*)(wsp + (size_t)R * 128 + sub * 8));
            __builtin_nontemporal_store(hi, (u32x2*)(wsp + (size_t)R * 128 + 64 + sub * 8));
        }
    } else {
        float* out = (float*)outbuf;
#pragma unroll
        for (int t = 0; t < 4; ++t) {
            const int R = r0 + rb + t * 8 + g;
#pragma unroll
            for (int k = 0; k < 4; ++k) {
                atomicAdd(out + (size_t)R * 64 + sub * 4 + k, acc[t][k]);
                atomicAdd(out + (size_t)R * 64 + 32 + sub * 4 + k, acc[t][k + 4]);
            }
        }
    }
}

__global__ __launch_bounds__(256)
void kan_reduce(const u32* __restrict__ ws, float* __restrict__ out) {
    const int i = blockIdx.x * 256 + threadIdx.x;   // u32x2 index (4 bf16), 131072
    const u32x2* w2 = (const u32x2*)ws;
    float a0 = 0.f, a1 = 0.f, a2 = 0.f, a3 = 0.f;
#pragma unroll
    for (int s = 0; s < N_SPLIT; ++s) {
        u32x2 v = __builtin_nontemporal_load(
            &w2[(size_t)s * (BATCH * OUT_DIM / 4) + i]);
        a0 += bflo(v.x); a1 += bfhi(v.x);
        a2 += bflo(v.y); a3 += bfhi(v.y);
    }
    f32x4 r = { a0, a1, a2, a3 };
    *(f32x4*)(out + (size_t)i * 4) = r;
}

extern "C" void kernel_launch(void* const* d_in, const int* in_sizes, int n_in,
                              void* d_out, int out_size, void* d_ws, size_t ws_size,
                              hipStream_t stream) {
    const float* X = (const float*)d_in[0];
    const float* W = (const float*)d_in[1];
    float* out = (float*)d_out;
    const size_t need = (size_t)N_SPLIT * BATCH * OUT_DIM * 2;   // bf16 planes
    dim3 grid(NM, N_SPLIT);
    if (ws_size >= need) {
        kan_main<<<grid, 512, 0, stream>>>(X, W, d_ws, 0);
        kan_reduce<<<(BATCH * OUT_DIM / 4) / 256, 256, 0, stream>>>((const u32*)d_ws, out);
    } else {
        (void)hipMemsetAsync(d_out, 0, (size_t)out_size * sizeof(float), stream);
        kan_main<<<grid, 512, 0, stream>>>(X, W, d_out, 1);
    }
}